// Round 1
// baseline (578.138 us; speedup 1.0000x reference)
//
#include <hip/hip_runtime.h>

// ProgressiveFocusedAttention, MI355X/gfx950.
// B=4, H=W=128, C=192, 6 heads x 32, window 8x8 (64 tokens), shift 4.
// 1024 windows. Outputs: out (4,128,128,192) fp32 then attn (1024,6,64,64) fp32.
//
// Pipeline: K0 pack weights->bf16 B-frag layout; K1 per-window QKV GEMM (bf16
// MFMA 16x16x32) + LePE conv; K2 per-(window,head) QK^T * prev -> softmax ->
// attn out + PV; K3 per-window proj GEMM + unshift scatter.
//
// MFMA 16x16x32 bf16 layouts (per guide, HW-verified):
//   A[m][k]: m = lane&15, k = (lane>>4)*8 + j   (8 contiguous bf16 per lane)
//   B[k][n]: n = lane&15, k = (lane>>4)*8 + j
//   D[r][c]: c = lane&15, r = (lane>>4)*4 + reg

#define SCALE 0.17677669529663687f

typedef __attribute__((ext_vector_type(8))) short short8;
typedef __attribute__((ext_vector_type(4))) float f32x4;

__device__ __forceinline__ unsigned short f2bf(float f) {
    unsigned int u = __float_as_uint(f);
    u = (u + 0x7FFFu + ((u >> 16) & 1u)) >> 16;   // round-to-nearest-even
    return (unsigned short)u;
}
__device__ __forceinline__ float bf2f(unsigned short h) {
    return __uint_as_float(((unsigned int)h) << 16);
}
__device__ __forceinline__ unsigned int pack2(float a, float b) {
    return (unsigned int)f2bf(a) | ((unsigned int)f2bf(b) << 16);
}

// ---------------------------------------------------------------- K0: pack
// qkv_w (192,576) and proj_w (192,192) fp32 -> bf16 in B-fragment order:
// flat[((ks*NT + nt)*64 + lane)*8 + j] = w[ks*32 + (lane>>4)*8 + j][nt*16 + (lane&15)]
__global__ __launch_bounds__(256) void k0_pack(const float* __restrict__ qkv_w,
                                               const float* __restrict__ proj_w,
                                               unsigned short* __restrict__ qkvp,
                                               unsigned short* __restrict__ projp) {
    int gid = blockIdx.x * 256 + threadIdx.x;   // grid covers 6*36*64 + 6*12*64 = 18432
    if (gid < 6 * 36 * 64) {
        int lane = gid & 63, tile = gid >> 6;
        int nt = tile % 36, ks = tile / 36;
        int row = ks * 32 + (lane >> 4) * 8, col = nt * 16 + (lane & 15);
        const float* w = qkv_w + (size_t)row * 576 + col;
        uint4 o;
        o.x = pack2(w[0 * 576], w[1 * 576]);
        o.y = pack2(w[2 * 576], w[3 * 576]);
        o.z = pack2(w[4 * 576], w[5 * 576]);
        o.w = pack2(w[6 * 576], w[7 * 576]);
        *(uint4*)(qkvp + (size_t)gid * 8) = o;
    } else {
        int g = gid - 6 * 36 * 64;
        int lane = g & 63, tile = g >> 6;
        int nt = tile % 12, ks = tile / 12;
        int row = ks * 32 + (lane >> 4) * 8, col = nt * 16 + (lane & 15);
        const float* w = proj_w + (size_t)row * 192 + col;
        uint4 o;
        o.x = pack2(w[0 * 192], w[1 * 192]);
        o.y = pack2(w[2 * 192], w[3 * 192]);
        o.z = pack2(w[4 * 192], w[5 * 192]);
        o.w = pack2(w[6 * 192], w[7 * 192]);
        *(uint4*)(projp + (size_t)g * 8) = o;
    }
}

// ---------------------------------------------------------------- K1: QKV + LePE
// One block per window (1024 blocks, 256 threads = 4 waves).
// LDS: xw 64x200 bf16 (25.6KB, +8 pad -> 2-way banks, free) + vT 192x72 bf16 (27.6KB).
__global__ __launch_bounds__(256) void k1_qkv(const float* __restrict__ x,
                                              const float* __restrict__ qkv_b,
                                              const float* __restrict__ lepe_w,
                                              const float* __restrict__ lepe_b,
                                              const unsigned short* __restrict__ qkvp,
                                              unsigned short* __restrict__ q_ws,
                                              unsigned short* __restrict__ k_ws,
                                              unsigned short* __restrict__ vt_ws) {
    __shared__ unsigned short xw[64 * 200];
    __shared__ unsigned short vt[192 * 72];
    const int wb = blockIdx.x;
    const int b = wb >> 8, wh = (wb >> 4) & 15, wwi = wb & 15;
    const int t = threadIdx.x;
    const int lane = t & 63, wave = t >> 6, quad = lane >> 4, l16 = lane & 15;

    // Phase 1: shifted-window load, fp32 -> bf16, into LDS rows (pitch 200).
    {
        int token = t >> 2, part = t & 3;
        int i = token >> 3, j = token & 7;
        int hh = (wh * 8 + i + 4) & 127, wp = (wwi * 8 + j + 4) & 127;
        const float4* src = (const float4*)(x + ((size_t)((b * 128 + hh) * 128 + wp)) * 192 + part * 48);
        unsigned int* dst = (unsigned int*)(xw + token * 200 + part * 48);
#pragma unroll
        for (int c = 0; c < 12; ++c) {
            float4 f = src[c];
            dst[2 * c] = pack2(f.x, f.y);
            dst[2 * c + 1] = pack2(f.z, f.w);
        }
    }
    __syncthreads();

    // Phase 2: qkv = xw(64x192) @ qkv_w(192x576).  Wave handles 9 N-tiles (144 cols).
    f32x4 acc[9][4];
#pragma unroll
    for (int n = 0; n < 9; n++)
#pragma unroll
        for (int m = 0; m < 4; m++) acc[n][m] = (f32x4){0.f, 0.f, 0.f, 0.f};

#pragma unroll
    for (int ks = 0; ks < 6; ks++) {
        short8 a[4];
#pragma unroll
        for (int m = 0; m < 4; m++)
            a[m] = *(const short8*)(xw + (m * 16 + l16) * 200 + ks * 32 + quad * 8);
#pragma unroll
        for (int n = 0; n < 9; n++) {
            int nt = wave * 9 + n;
            short8 bf = *(const short8*)(qkvp + (((size_t)(ks * 36 + nt) * 64 + lane) << 3));
#pragma unroll
            for (int m = 0; m < 4; m++)
                acc[n][m] = __builtin_amdgcn_mfma_f32_16x16x32_bf16(a[m], bf, acc[n][m], 0, 0, 0);
        }
    }

    // Epilogue: +bias; q,k -> global row-major bf16; v -> LDS transposed [c][token].
#pragma unroll
    for (int n = 0; n < 9; n++) {
        int col = (wave * 9 + n) * 16 + l16;
        float bias = qkv_b[col];
#pragma unroll
        for (int m = 0; m < 4; m++) {
#pragma unroll
            for (int r = 0; r < 4; r++) {
                float v = acc[n][m][r] + bias;
                int token = m * 16 + quad * 4 + r;
                if (col < 192) {
                    q_ws[((size_t)wb * 64 + token) * 192 + col] = f2bf(v);
                } else if (col < 384) {
                    k_ws[((size_t)wb * 64 + token) * 192 + (col - 192)] = f2bf(v);
                } else {
                    vt[(col - 384) * 72 + token] = f2bf(v);
                }
            }
        }
    }
    __syncthreads();

    // Phase 3: LePE 3x3 depthwise conv (zero-pad inside 8x8 window) + residual v.
    for (int idx = t; idx < 192 * 64; idx += 256) {
        int c = idx >> 6, token = idx & 63;      // c wave-uniform -> scalar weight loads
        int i = token >> 3, j = token & 7;
        float sum = bf2f(vt[c * 72 + token]) + lepe_b[c];
#pragma unroll
        for (int di = -1; di <= 1; di++) {
#pragma unroll
            for (int dj = -1; dj <= 1; dj++) {
                int ii = i + di, jj = j + dj;
                if (ii >= 0 && ii < 8 && jj >= 0 && jj < 8)
                    sum += bf2f(vt[c * 72 + ii * 8 + jj]) * lepe_w[((di + 1) * 3 + (dj + 1)) * 192 + c];
            }
        }
        vt_ws[((size_t)wb * 192 + c) * 64 + token] = f2bf(sum);
    }
}

// ---------------------------------------------------------------- K2: attention
// One block per (window, head): 6144 blocks, 4 waves; wave w owns M-tile w (rows 16w..16w+15).
__global__ __launch_bounds__(256) void k2_attn(const unsigned short* __restrict__ q_ws,
                                               const unsigned short* __restrict__ k_ws,
                                               const unsigned short* __restrict__ vt_ws,
                                               const float* __restrict__ prev,
                                               float* __restrict__ attn_out,
                                               unsigned short* __restrict__ o_ws) {
    __shared__ unsigned short S[64 * 72];
    const int bid = blockIdx.x;
    const int wb = bid / 6, h = bid - wb * 6;
    const int t = threadIdx.x;
    const int lane = t & 63, mt = t >> 6, quad = lane >> 4, l16 = lane & 15;

    // QK^T: A = q rows, B = k^T (k rows loaded as A-style frags give B of k^T).
    const size_t qkbase = (size_t)wb * 64 * 192 + h * 32 + quad * 8;
    short8 a = *(const short8*)(q_ws + qkbase + (size_t)(mt * 16 + l16) * 192);
    f32x4 acc[4];
#pragma unroll
    for (int nt = 0; nt < 4; nt++) acc[nt] = (f32x4){0.f, 0.f, 0.f, 0.f};
#pragma unroll
    for (int nt = 0; nt < 4; nt++) {
        short8 bk = *(const short8*)(k_ws + qkbase + (size_t)(nt * 16 + l16) * 192);
        acc[nt] = __builtin_amdgcn_mfma_f32_16x16x32_bf16(a, bk, acc[nt], 0, 0, 0);
    }

    // Gate with prev_attn_map, softmax over 64 cols (fp32; |scores| < ~0.5 so no max-sub needed).
    const float* pv = prev + (((size_t)wb * 6 + h) << 12);
    float* ao = attn_out + (((size_t)wb * 6 + h) << 12);
    float e[4][4];
    float psum[4];
#pragma unroll
    for (int r = 0; r < 4; r++) {
        int row = mt * 16 + quad * 4 + r;
        psum[r] = 0.f;
#pragma unroll
        for (int nt = 0; nt < 4; nt++) {
            int col = nt * 16 + l16;
            float sg = acc[nt][r] * SCALE * pv[row * 64 + col];
            float ev = __expf(sg);
            e[r][nt] = ev;
            psum[r] += ev;
        }
    }
#pragma unroll
    for (int r = 0; r < 4; r++) {
        psum[r] += __shfl_xor(psum[r], 1);
        psum[r] += __shfl_xor(psum[r], 2);
        psum[r] += __shfl_xor(psum[r], 4);
        psum[r] += __shfl_xor(psum[r], 8);   // full row sum (16 lanes x 4 tiles)
        psum[r] = 1.0f / psum[r];
    }
#pragma unroll
    for (int r = 0; r < 4; r++) {
        int row = mt * 16 + quad * 4 + r;
#pragma unroll
        for (int nt = 0; nt < 4; nt++) {
            int col = nt * 16 + l16;
            float av = e[r][nt] * psum[r];
            ao[row * 64 + col] = av;              // fp32 attn output
            S[row * 72 + col] = f2bf(av);         // D-layout -> LDS rows for A-frag reload
        }
    }
    __syncthreads();

    // PV: out_h(64x32) = attn(64x64) @ v_h(64x32); B from transposed v (vt_ws[c][token]).
    f32x4 acc2[2];
    acc2[0] = (f32x4){0.f, 0.f, 0.f, 0.f};
    acc2[1] = (f32x4){0.f, 0.f, 0.f, 0.f};
    const unsigned short* vb = vt_ws + ((size_t)wb * 192 + h * 32) * 64;
#pragma unroll
    for (int ks = 0; ks < 2; ks++) {
        short8 ap = *(const short8*)(S + (mt * 16 + l16) * 72 + ks * 32 + quad * 8);
#pragma unroll
        for (int n2 = 0; n2 < 2; n2++) {
            short8 bv = *(const short8*)(vb + (size_t)(n2 * 16 + l16) * 64 + ks * 32 + quad * 8);
            acc2[n2] = __builtin_amdgcn_mfma_f32_16x16x32_bf16(ap, bv, acc2[n2], 0, 0, 0);
        }
    }
#pragma unroll
    for (int n2 = 0; n2 < 2; n2++) {
#pragma unroll
        for (int r = 0; r < 4; r++) {
            int row = mt * 16 + quad * 4 + r;
            int c = h * 32 + n2 * 16 + l16;
            o_ws[((size_t)wb * 64 + row) * 192 + c] = f2bf(acc2[n2][r]);
        }
    }
}

// ---------------------------------------------------------------- K3: proj + unshift
__global__ __launch_bounds__(256) void k3_proj(const unsigned short* __restrict__ o_ws,
                                               const unsigned short* __restrict__ projp,
                                               const float* __restrict__ proj_b,
                                               float* __restrict__ out) {
    __shared__ unsigned short ol[64 * 200];
    const int wb = blockIdx.x;
    const int b = wb >> 8, wh = (wb >> 4) & 15, wwi = wb & 15;
    const int t = threadIdx.x;
    const int lane = t & 63, wave = t >> 6, quad = lane >> 4, l16 = lane & 15;

    {
        int token = t >> 2, part = t & 3;
        const uint4* src = (const uint4*)(o_ws + ((size_t)wb * 64 + token) * 192 + part * 48);
        uint4* dst = (uint4*)(ol + token * 200 + part * 48);
#pragma unroll
        for (int c = 0; c < 6; ++c) dst[c] = src[c];
    }
    __syncthreads();

    f32x4 acc[3][4];
#pragma unroll
    for (int n = 0; n < 3; n++)
#pragma unroll
        for (int m = 0; m < 4; m++) acc[n][m] = (f32x4){0.f, 0.f, 0.f, 0.f};

#pragma unroll
    for (int ks = 0; ks < 6; ks++) {
        short8 a[4];
#pragma unroll
        for (int m = 0; m < 4; m++)
            a[m] = *(const short8*)(ol + (m * 16 + l16) * 200 + ks * 32 + quad * 8);
#pragma unroll
        for (int n = 0; n < 3; n++) {
            int nt = wave * 3 + n;
            short8 bf = *(const short8*)(projp + (((size_t)(ks * 12 + nt) * 64 + lane) << 3));
#pragma unroll
            for (int m = 0; m < 4; m++)
                acc[n][m] = __builtin_amdgcn_mfma_f32_16x16x32_bf16(a[m], bf, acc[n][m], 0, 0, 0);
        }
    }
#pragma unroll
    for (int n = 0; n < 3; n++) {
        int col = (wave * 3 + n) * 16 + l16;
        float bias = proj_b[col];
#pragma unroll
        for (int m = 0; m < 4; m++) {
#pragma unroll
            for (int r = 0; r < 4; r++) {
                int token = m * 16 + quad * 4 + r;
                int i = token >> 3, j = token & 7;
                int hh = (wh * 8 + i + 4) & 127, wp = (wwi * 8 + j + 4) & 127;
                out[((size_t)((b * 128 + hh) * 128 + wp)) * 192 + col] = acc[n][m][r] + bias;
            }
        }
    }
}

// ---------------------------------------------------------------- launch
extern "C" void kernel_launch(void* const* d_in, const int* in_sizes, int n_in,
                              void* d_out, int out_size, void* d_ws, size_t ws_size,
                              hipStream_t stream) {
    const float* x      = (const float*)d_in[0];
    const float* prev   = (const float*)d_in[1];
    const float* qkv_w  = (const float*)d_in[2];
    const float* qkv_b  = (const float*)d_in[3];
    const float* proj_w = (const float*)d_in[4];
    const float* proj_b = (const float*)d_in[5];
    const float* lepe_w = (const float*)d_in[6];
    const float* lepe_b = (const float*)d_in[7];

    float* out  = (float*)d_out;
    float* attn = out + (size_t)4 * 128 * 128 * 192;   // second output, concatenated

    char* ws = (char*)d_ws;
    const size_t SZ_QKVP = 192 * 576 * 2;              // 221184
    const size_t SZ_PROJP = 192 * 192 * 2;             // 73728
    const size_t SZ_BUF = (size_t)1024 * 64 * 192 * 2; // 25165824 (bf16 token-major)
    unsigned short* qkvp  = (unsigned short*)(ws);
    unsigned short* projp = (unsigned short*)(ws + SZ_QKVP);
    unsigned short* q_ws  = (unsigned short*)(ws + SZ_QKVP + SZ_PROJP);
    unsigned short* k_ws  = (unsigned short*)(ws + SZ_QKVP + SZ_PROJP + SZ_BUF);
    unsigned short* vt_ws = (unsigned short*)(ws + SZ_QKVP + SZ_PROJP + 2 * SZ_BUF);
    unsigned short* o_ws  = (unsigned short*)(ws + SZ_QKVP + SZ_PROJP + 3 * SZ_BUF);
    // total ws use: ~96.3 MB

    k0_pack<<<72, 256, 0, stream>>>(qkv_w, proj_w, qkvp, projp);
    k1_qkv<<<1024, 256, 0, stream>>>(x, qkv_b, lepe_w, lepe_b, qkvp, q_ws, k_ws, vt_ws);
    k2_attn<<<6144, 256, 0, stream>>>(q_ws, k_ws, vt_ws, prev, attn, o_ws);
    k3_proj<<<1024, 256, 0, stream>>>(o_ws, projp, proj_b, out);
}

// Round 3
// 421.238 us; speedup vs baseline: 1.3725x; 1.3725x over previous
//
#include <hip/hip_runtime.h>

// ProgressiveFocusedAttention, MI355X/gfx950.
// B=4, H=W=128, C=192, 6 heads x 32, window 8x8 (64 tokens), shift 4.
// 1024 windows. Outputs: out (4,128,128,192) fp32 then attn (1024,6,64,64) fp32.
//
// R3: fix R2's copy-width bug (48 bf16 chunk = 6 uint4, not 3) in K1 copy-out
// and K3 staging. Structure unchanged from R2: K1 N-split into 3 slabs
// (grid 3072), acc[3][4] per wave, LDS-staged coalesced epilogue.
//
// MFMA 16x16x32 bf16 layouts (per guide, HW-verified):
//   A[m][k]: m = lane&15, k = (lane>>4)*8 + j   (8 contiguous bf16 per lane)
//   B[k][n]: n = lane&15, k = (lane>>4)*8 + j
//   D[r][c]: c = lane&15, r = (lane>>4)*4 + reg

#define SCALE 0.17677669529663687f

typedef __attribute__((ext_vector_type(8))) short short8;
typedef __attribute__((ext_vector_type(4))) float f32x4;

__device__ __forceinline__ unsigned short f2bf(float f) {
    unsigned int u = __float_as_uint(f);
    u = (u + 0x7FFFu + ((u >> 16) & 1u)) >> 16;   // round-to-nearest-even
    return (unsigned short)u;
}
__device__ __forceinline__ float bf2f(unsigned short h) {
    return __uint_as_float(((unsigned int)h) << 16);
}
__device__ __forceinline__ unsigned int pack2(float a, float b) {
    return (unsigned int)f2bf(a) | ((unsigned int)f2bf(b) << 16);
}

// ---------------------------------------------------------------- K0: pack
// qkv_w (192,576) and proj_w (192,192) fp32 -> bf16 in B-fragment order:
// flat[((ks*NT + nt)*64 + lane)*8 + j] = w[ks*32 + (lane>>4)*8 + j][nt*16 + (lane&15)]
__global__ __launch_bounds__(256) void k0_pack(const float* __restrict__ qkv_w,
                                               const float* __restrict__ proj_w,
                                               unsigned short* __restrict__ qkvp,
                                               unsigned short* __restrict__ projp) {
    int gid = blockIdx.x * 256 + threadIdx.x;   // grid covers 6*36*64 + 6*12*64 = 18432
    if (gid < 6 * 36 * 64) {
        int lane = gid & 63, tile = gid >> 6;
        int nt = tile % 36, ks = tile / 36;
        int row = ks * 32 + (lane >> 4) * 8, col = nt * 16 + (lane & 15);
        const float* w = qkv_w + (size_t)row * 576 + col;
        uint4 o;
        o.x = pack2(w[0 * 576], w[1 * 576]);
        o.y = pack2(w[2 * 576], w[3 * 576]);
        o.z = pack2(w[4 * 576], w[5 * 576]);
        o.w = pack2(w[6 * 576], w[7 * 576]);
        *(uint4*)(qkvp + (size_t)gid * 8) = o;
    } else {
        int g = gid - 6 * 36 * 64;
        int lane = g & 63, tile = g >> 6;
        int nt = tile % 12, ks = tile / 12;
        int row = ks * 32 + (lane >> 4) * 8, col = nt * 16 + (lane & 15);
        const float* w = proj_w + (size_t)row * 192 + col;
        uint4 o;
        o.x = pack2(w[0 * 192], w[1 * 192]);
        o.y = pack2(w[2 * 192], w[3 * 192]);
        o.z = pack2(w[4 * 192], w[5 * 192]);
        o.w = pack2(w[6 * 192], w[7 * 192]);
        *(uint4*)(projp + (size_t)g * 8) = o;
    }
}

// ---------------------------------------------------------------- K1: QKV + LePE
// Grid 3072 = 3 slabs x 1024 windows; block 256 (4 waves).
// Slab s computes output cols [s*192, s*192+192): s=0 -> q, s=1 -> k, s=2 -> v(+LePE).
// Wave handles 3 N-tiles -> acc[3][4] (48 regs). LDS: one 64x200 bf16 buffer
// (25.6 KB), reused: x-window for MFMA, then result staging / conv scratch.
__global__ __launch_bounds__(256) void k1_qkv(const float* __restrict__ x,
                                              const float* __restrict__ qkv_b,
                                              const float* __restrict__ lepe_w,
                                              const float* __restrict__ lepe_b,
                                              const unsigned short* __restrict__ qkvp,
                                              unsigned short* __restrict__ q_ws,
                                              unsigned short* __restrict__ k_ws,
                                              unsigned short* __restrict__ vt_ws) {
    __shared__ unsigned short xw[64 * 200];
    const int bid = blockIdx.x;
    const int s = bid >> 10, wb = bid & 1023;
    const int b = wb >> 8, wh = (wb >> 4) & 15, wwi = wb & 15;
    const int t = threadIdx.x;
    const int lane = t & 63, wave = t >> 6, quad = lane >> 4, l16 = lane & 15;

    // Phase 1: shifted-window load, fp32 -> bf16, into LDS rows (pitch 200, 16B-aligned rows).
    {
        int token = t >> 2, part = t & 3;
        int i = token >> 3, j = token & 7;
        int hh = (wh * 8 + i + 4) & 127, wp = (wwi * 8 + j + 4) & 127;
        const float4* src = (const float4*)(x + ((size_t)((b * 128 + hh) * 128 + wp)) * 192 + part * 48);
        unsigned int* dst = (unsigned int*)(xw + token * 200 + part * 48);
#pragma unroll
        for (int c = 0; c < 12; ++c) {
            float4 f = src[c];
            dst[2 * c] = pack2(f.x, f.y);
            dst[2 * c + 1] = pack2(f.z, f.w);
        }
    }
    __syncthreads();

    // Phase 2: this slab's 12 N-tiles of qkv = xw(64x192) @ qkv_w(192x576); 3 per wave.
    f32x4 acc[3][4];
#pragma unroll
    for (int n = 0; n < 3; n++)
#pragma unroll
        for (int m = 0; m < 4; m++) acc[n][m] = (f32x4){0.f, 0.f, 0.f, 0.f};

#pragma unroll
    for (int ks = 0; ks < 6; ks++) {
        short8 a[4];
#pragma unroll
        for (int m = 0; m < 4; m++)
            a[m] = *(const short8*)(xw + (m * 16 + l16) * 200 + ks * 32 + quad * 8);
#pragma unroll
        for (int n = 0; n < 3; n++) {
            int ntg = s * 12 + wave * 3 + n;
            short8 bf = *(const short8*)(qkvp + (((size_t)(ks * 36 + ntg) * 64 + lane) << 3));
#pragma unroll
            for (int m = 0; m < 4; m++)
                acc[n][m] = __builtin_amdgcn_mfma_f32_16x16x32_bf16(a[m], bf, acc[n][m], 0, 0, 0);
        }
    }
    __syncthreads();   // all waves done reading xw; reuse it for staging

    // Epilogue: +bias, bf16, stage into LDS at [token*200 + local_col].
#pragma unroll
    for (int n = 0; n < 3; n++) {
        int lcol = (wave * 3 + n) * 16 + l16;
        float bias = qkv_b[s * 192 + lcol];
#pragma unroll
        for (int m = 0; m < 4; m++) {
#pragma unroll
            for (int r = 0; r < 4; r++) {
                int token = m * 16 + quad * 4 + r;
                xw[token * 200 + lcol] = f2bf(acc[n][m][r] + bias);
            }
        }
    }
    __syncthreads();

    if (s < 2) {
        // Coalesced copy-out: 64 tokens x 192 bf16 rows -> q_ws / k_ws.
        // Each thread: 48-bf16 chunk = 96 B = 6 uint4.
        unsigned short* dstg = (s == 0) ? q_ws : k_ws;
        int token = t >> 2, part = t & 3;
        const uint4* srcl = (const uint4*)(xw + token * 200 + part * 48);
        uint4* dg = (uint4*)(dstg + ((size_t)wb * 64 + token) * 192 + part * 48);
#pragma unroll
        for (int c = 0; c < 6; ++c) dg[c] = srcl[c];
    } else {
        // LePE 3x3 depthwise conv (zero-pad inside 8x8 window) + residual v;
        // store channel-major [c][token] (coalesced: token = lane).
        for (int idx = t; idx < 192 * 64; idx += 256) {
            int c = idx >> 6, token = idx & 63;   // c wave-uniform
            int i = token >> 3, j = token & 7;
            float sum = bf2f(xw[token * 200 + c]) + lepe_b[c];
#pragma unroll
            for (int di = -1; di <= 1; di++) {
#pragma unroll
                for (int dj = -1; dj <= 1; dj++) {
                    int ii = i + di, jj = j + dj;
                    if (ii >= 0 && ii < 8 && jj >= 0 && jj < 8)
                        sum += bf2f(xw[(ii * 8 + jj) * 200 + c]) * lepe_w[((di + 1) * 3 + (dj + 1)) * 192 + c];
                }
            }
            vt_ws[((size_t)wb * 192 + c) * 64 + token] = f2bf(sum);
        }
    }
}

// ---------------------------------------------------------------- K2: attention
// One block per (window, head): 6144 blocks, 4 waves; wave w owns M-tile w (rows 16w..16w+15).
__global__ __launch_bounds__(256) void k2_attn(const unsigned short* __restrict__ q_ws,
                                               const unsigned short* __restrict__ k_ws,
                                               const unsigned short* __restrict__ vt_ws,
                                               const float* __restrict__ prev,
                                               float* __restrict__ attn_out,
                                               unsigned short* __restrict__ o_ws) {
    __shared__ unsigned short S[64 * 72];
    const int bid = blockIdx.x;
    const int wb = bid / 6, h = bid - wb * 6;
    const int t = threadIdx.x;
    const int lane = t & 63, mt = t >> 6, quad = lane >> 4, l16 = lane & 15;

    // QK^T: A = q rows, B = k^T (k rows loaded as A-style frags give B of k^T).
    const size_t qkbase = (size_t)wb * 64 * 192 + h * 32 + quad * 8;
    short8 a = *(const short8*)(q_ws + qkbase + (size_t)(mt * 16 + l16) * 192);
    f32x4 acc[4];
#pragma unroll
    for (int nt = 0; nt < 4; nt++) acc[nt] = (f32x4){0.f, 0.f, 0.f, 0.f};
#pragma unroll
    for (int nt = 0; nt < 4; nt++) {
        short8 bk = *(const short8*)(k_ws + qkbase + (size_t)(nt * 16 + l16) * 192);
        acc[nt] = __builtin_amdgcn_mfma_f32_16x16x32_bf16(a, bk, acc[nt], 0, 0, 0);
    }

    // Gate with prev_attn_map, softmax over 64 cols (fp32; |scores| < ~0.5 so no max-sub needed).
    const float* pv = prev + (((size_t)wb * 6 + h) << 12);
    float* ao = attn_out + (((size_t)wb * 6 + h) << 12);
    float e[4][4];
    float psum[4];
#pragma unroll
    for (int r = 0; r < 4; r++) {
        int row = mt * 16 + quad * 4 + r;
        psum[r] = 0.f;
#pragma unroll
        for (int nt = 0; nt < 4; nt++) {
            int col = nt * 16 + l16;
            float sg = acc[nt][r] * SCALE * pv[row * 64 + col];
            float ev = __expf(sg);
            e[r][nt] = ev;
            psum[r] += ev;
        }
    }
#pragma unroll
    for (int r = 0; r < 4; r++) {
        psum[r] += __shfl_xor(psum[r], 1);
        psum[r] += __shfl_xor(psum[r], 2);
        psum[r] += __shfl_xor(psum[r], 4);
        psum[r] += __shfl_xor(psum[r], 8);   // full row sum (16 lanes x 4 tiles)
        psum[r] = 1.0f / psum[r];
    }
#pragma unroll
    for (int r = 0; r < 4; r++) {
        int row = mt * 16 + quad * 4 + r;
#pragma unroll
        for (int nt = 0; nt < 4; nt++) {
            int col = nt * 16 + l16;
            float av = e[r][nt] * psum[r];
            ao[row * 64 + col] = av;              // fp32 attn output
            S[row * 72 + col] = f2bf(av);         // D-layout -> LDS rows for A-frag reload
        }
    }
    __syncthreads();

    // PV: out_h(64x32) = attn(64x64) @ v_h(64x32); B from transposed v (vt_ws[c][token]).
    f32x4 acc2[2];
    acc2[0] = (f32x4){0.f, 0.f, 0.f, 0.f};
    acc2[1] = (f32x4){0.f, 0.f, 0.f, 0.f};
    const unsigned short* vb = vt_ws + ((size_t)wb * 192 + h * 32) * 64;
#pragma unroll
    for (int ks = 0; ks < 2; ks++) {
        short8 ap = *(const short8*)(S + (mt * 16 + l16) * 72 + ks * 32 + quad * 8);
#pragma unroll
        for (int n2 = 0; n2 < 2; n2++) {
            short8 bv = *(const short8*)(vb + (size_t)(n2 * 16 + l16) * 64 + ks * 32 + quad * 8);
            acc2[n2] = __builtin_amdgcn_mfma_f32_16x16x32_bf16(ap, bv, acc2[n2], 0, 0, 0);
        }
    }
#pragma unroll
    for (int n2 = 0; n2 < 2; n2++) {
#pragma unroll
        for (int r = 0; r < 4; r++) {
            int row = mt * 16 + quad * 4 + r;
            int c = h * 32 + n2 * 16 + l16;
            o_ws[((size_t)wb * 64 + row) * 192 + c] = f2bf(acc2[n2][r]);
        }
    }
}

// ---------------------------------------------------------------- K3: proj + unshift
__global__ __launch_bounds__(256) void k3_proj(const unsigned short* __restrict__ o_ws,
                                               const unsigned short* __restrict__ projp,
                                               const float* __restrict__ proj_b,
                                               float* __restrict__ out) {
    __shared__ unsigned short ol[64 * 200];
    const int wb = blockIdx.x;
    const int b = wb >> 8, wh = (wb >> 4) & 15, wwi = wb & 15;
    const int t = threadIdx.x;
    const int lane = t & 63, wave = t >> 6, quad = lane >> 4, l16 = lane & 15;

    {
        // Each thread: 48-bf16 chunk = 96 B = 6 uint4.
        int token = t >> 2, part = t & 3;
        const uint4* src = (const uint4*)(o_ws + ((size_t)wb * 64 + token) * 192 + part * 48);
        uint4* dst = (uint4*)(ol + token * 200 + part * 48);
#pragma unroll
        for (int c = 0; c < 6; ++c) dst[c] = src[c];
    }
    __syncthreads();

    f32x4 acc[3][4];
#pragma unroll
    for (int n = 0; n < 3; n++)
#pragma unroll
        for (int m = 0; m < 4; m++) acc[n][m] = (f32x4){0.f, 0.f, 0.f, 0.f};

#pragma unroll
    for (int ks = 0; ks < 6; ks++) {
        short8 a[4];
#pragma unroll
        for (int m = 0; m < 4; m++)
            a[m] = *(const short8*)(ol + (m * 16 + l16) * 200 + ks * 32 + quad * 8);
#pragma unroll
        for (int n = 0; n < 3; n++) {
            int nt = wave * 3 + n;
            short8 bf = *(const short8*)(projp + (((size_t)(ks * 12 + nt) * 64 + lane) << 3));
#pragma unroll
            for (int m = 0; m < 4; m++)
                acc[n][m] = __builtin_amdgcn_mfma_f32_16x16x32_bf16(a[m], bf, acc[n][m], 0, 0, 0);
        }
    }
#pragma unroll
    for (int n = 0; n < 3; n++) {
        int col = (wave * 3 + n) * 16 + l16;
        float bias = proj_b[col];
#pragma unroll
        for (int m = 0; m < 4; m++) {
#pragma unroll
            for (int r = 0; r < 4; r++) {
                int token = m * 16 + quad * 4 + r;
                int i = token >> 3, j = token & 7;
                int hh = (wh * 8 + i + 4) & 127, wp = (wwi * 8 + j + 4) & 127;
                out[((size_t)((b * 128 + hh) * 128 + wp)) * 192 + col] = acc[n][m][r] + bias;
            }
        }
    }
}

// ---------------------------------------------------------------- launch
extern "C" void kernel_launch(void* const* d_in, const int* in_sizes, int n_in,
                              void* d_out, int out_size, void* d_ws, size_t ws_size,
                              hipStream_t stream) {
    const float* x      = (const float*)d_in[0];
    const float* prev   = (const float*)d_in[1];
    const float* qkv_w  = (const float*)d_in[2];
    const float* qkv_b  = (const float*)d_in[3];
    const float* proj_w = (const float*)d_in[4];
    const float* proj_b = (const float*)d_in[5];
    const float* lepe_w = (const float*)d_in[6];
    const float* lepe_b = (const float*)d_in[7];

    float* out  = (float*)d_out;
    float* attn = out + (size_t)4 * 128 * 128 * 192;   // second output, concatenated

    char* ws = (char*)d_ws;
    const size_t SZ_QKVP = 192 * 576 * 2;              // 221184
    const size_t SZ_PROJP = 192 * 192 * 2;             // 73728
    const size_t SZ_BUF = (size_t)1024 * 64 * 192 * 2; // 25165824 (bf16 token-major)
    unsigned short* qkvp  = (unsigned short*)(ws);
    unsigned short* projp = (unsigned short*)(ws + SZ_QKVP);
    unsigned short* q_ws  = (unsigned short*)(ws + SZ_QKVP + SZ_PROJP);
    unsigned short* k_ws  = (unsigned short*)(ws + SZ_QKVP + SZ_PROJP + SZ_BUF);
    unsigned short* vt_ws = (unsigned short*)(ws + SZ_QKVP + SZ_PROJP + 2 * SZ_BUF);
    unsigned short* o_ws  = (unsigned short*)(ws + SZ_QKVP + SZ_PROJP + 3 * SZ_BUF);
    // total ws use: ~96.3 MB

    k0_pack<<<72, 256, 0, stream>>>(qkv_w, proj_w, qkvp, projp);
    k1_qkv<<<3072, 256, 0, stream>>>(x, qkv_b, lepe_w, lepe_b, qkvp, q_ws, k_ws, vt_ws);
    k2_attn<<<6144, 256, 0, stream>>>(q_ws, k_ws, vt_ws, prev, attn, o_ws);
    k3_proj<<<1024, 256, 0, stream>>>(o_ws, projp, proj_b, out);
}